// Round 11
// baseline (121.199 us; speedup 1.0000x reference)
//
#include <hip/hip_runtime.h>
#include <hip/hip_bf16.h>

// MultiLinear: y[b,g,o] = sum_i x[b,g,i] * W[g,o,i] + bias[g,o]
// B=4096, G=16, DIN=512, DOUT=512, fp32 in/out.
// R11: BOTH operands DMA-staged (global_load_lds), zero wave-side staging.
//  - A staged as RAW FP32 (no X prepass); fp32->bf16 cvt at consume time.
//  - B staged bf16 from W-prepass (d_ws).
//  - 128x128 tile, BK=32, 4 waves, dbuf LDS = 48 KB -> 3 blocks/CU
//    (launch_bounds(256,3): acc 64 AGPR + ~60 arch regs <= 170 bin).
//  - One raw barrier/K-step; per-wave vmcnt(0) BEFORE barrier publishes its
//    own DMA writes (RAW); post-barrier DMA refill is WAR-safe (all reads of
//    the target buffer consumed pre-barrier).
//  - T21 both-sides swizzle: A 32B-granule XOR(row&3), B 16B-chunk XOR(row&3);
//    pre-swizzled GLOBAL source + swizzled ds_read, linear LDS dest.

#define BATCH 4096
#define NGRP  16
#define DIN   512
#define DOUT  512

#define BM 128
#define BN 128
#define BK 32
#define NT (DIN / BK)   // 16 K-steps

typedef __bf16 bf16x8 __attribute__((ext_vector_type(8)));
typedef float  f32x4  __attribute__((ext_vector_type(4)));
typedef const __attribute__((address_space(1))) void gas_void;
typedef __attribute__((address_space(3))) void las_void;

// ---------- prepass: W fp32 -> bf16 into d_ws (canonical layout) ----------
__global__ __launch_bounds__(256)
void wcvt_kernel(const float* __restrict__ W, __bf16* __restrict__ Wb) {
    const int i = (blockIdx.x * 256 + threadIdx.x) * 8;
    f32x4 a = *(const f32x4*)(W + i);
    f32x4 b = *(const f32x4*)(W + i + 4);
    bf16x8 v;
#pragma unroll
    for (int j = 0; j < 4; ++j) { v[j] = (__bf16)a[j]; v[j + 4] = (__bf16)b[j]; }
    *(bf16x8*)(Wb + i) = v;
}

// ---------- main GEMM ----------
__global__ __launch_bounds__(256, 3)
void MultiLinear_48498770706571_kernel(const float* __restrict__ X,
                                       const __bf16* __restrict__ Wb,
                                       const float* __restrict__ Bias,
                                       float* __restrict__ Y) {
    // 2048 blocks / 8 XCDs = 256 consecutive tiles (2 full groups) per XCD.
    const int bid = (blockIdx.x & 7) * 256 + (blockIdx.x >> 3);
    const int grp = bid >> 7;          // 128 tiles per group (32 m x 4 n)
    const int mt  = (bid >> 2) & 31;
    const int nt  = bid & 3;
    const int bm0 = mt * BM;
    const int bn0 = nt * BN;

    __shared__ float  As[2][BM][BK];    // 32 KB: raw fp32, DMA-filled
    __shared__ __bf16 Bs[2][BN * BK];   // 16 KB: bf16, DMA-filled

    const int tid  = threadIdx.x;
    const int lane = tid & 63;
    const int w    = tid >> 6;        // 0..3
    const int wm   = (w >> 1) * 64;   // {0,64}
    const int wn   = (w & 1) * 64;    // {0,64}
    const int l15  = lane & 15;
    const int q    = lane >> 4;       // 0..3 = k-granule of the MFMA frag

    // A-DMA per-lane geometry: instr covers 8 rows x 128 B (1 KB).
    const int arow_l = lane >> 3;     // 0..7: row within instr
    const int ag     = (lane & 7) >> 1;  // 32B granule 0..3 in LDS
    const int ah     = lane & 1;         // 16B half within granule
    // B-DMA per-lane geometry: instr covers 16 rows x 64 B (1 KB).
    const int brow_l = lane >> 2;     // 0..15
    const int bc     = lane & 3;      // 16B chunk 0..3 in LDS

    const float*  xbase = X + ((size_t)bm0 * NGRP + grp) * DIN;
    const __bf16* wbase = Wb + (size_t)(grp * DOUT + bn0) * DIN;

    // A: LDS granule ag of row r holds GLOBAL granule ag^(r&3) (XOR involution)
#define DMA_A(kt, buf)                                                     \
    do {                                                                   \
        _Pragma("unroll")                                                  \
        for (int q4 = 0; q4 < 4; ++q4) {                                   \
            const int row0 = (w << 5) + (q4 << 3);                         \
            const int r    = row0 + arow_l;                                \
            const int gsrc = ag ^ (r & 3);                                 \
            const float* gp = xbase + (size_t)r * (NGRP * DIN)             \
                              + (kt) * BK + (gsrc << 3) + (ah << 2);       \
            __builtin_amdgcn_global_load_lds(                              \
                (gas_void*)gp, (las_void*)&As[buf][row0][0], 16, 0, 0);    \
        }                                                                  \
    } while (0)

    // B: LDS chunk bc of row r holds GLOBAL chunk bc^(r&3)
#define DMA_B(kt, buf)                                                     \
    do {                                                                   \
        _Pragma("unroll")                                                  \
        for (int q2 = 0; q2 < 2; ++q2) {                                   \
            const int row0 = (w << 5) + (q2 << 4);                         \
            const int r    = row0 + brow_l;                                \
            const int csrc = bc ^ (r & 3);                                 \
            const __bf16* gp = wbase + (size_t)r * DIN                     \
                               + (kt) * BK + (csrc << 3);                  \
            __builtin_amdgcn_global_load_lds(                              \
                (gas_void*)gp, (las_void*)&Bs[buf][row0 * BK], 16, 0, 0);  \
        }                                                                  \
    } while (0)

    f32x4 acc[4][4];
#pragma unroll
    for (int mi = 0; mi < 4; ++mi)
#pragma unroll
        for (int ni = 0; ni < 4; ++ni) acc[mi][ni] = f32x4{0.f, 0.f, 0.f, 0.f};

    // prologue: DMA tile 0 into buf 0
    DMA_A(0, 0);
    DMA_B(0, 0);

    for (int kt = 0; kt < NT; ++kt) {
        const int cur = kt & 1;
        // Publish own DMA(kt) writes (RAW), then sync. DMA had the whole
        // previous compute phase to land -> this drain is cheap.
        asm volatile("s_waitcnt vmcnt(0)" ::: "memory");
        asm volatile("s_waitcnt lgkmcnt(0)" ::: "memory");
        __builtin_amdgcn_s_barrier();

        // WAR-safe refill: every wave consumed its buf^1 reads pre-barrier.
        if (kt + 1 < NT) {
            DMA_A(kt + 1, cur ^ 1);
            DMA_B(kt + 1, cur ^ 1);
        }

        // consume: ds_read fp32 A (swizzled) + in-reg cvt, ds_read bf16 B
        bf16x8 af[4], bfr[4];
#pragma unroll
        for (int mi = 0; mi < 4; ++mi) {
            const int row = wm + mi * 16 + l15;
            const int gl  = q ^ (row & 3);
            const f32x4* pa = (const f32x4*)&As[cur][row][gl << 3];
            f32x4 x0 = pa[0], x1 = pa[1];
#pragma unroll
            for (int j = 0; j < 4; ++j) {
                af[mi][j]     = (__bf16)x0[j];
                af[mi][j + 4] = (__bf16)x1[j];
            }
        }
#pragma unroll
        for (int ni = 0; ni < 4; ++ni) {
            const int brow = wn + ni * 16 + l15;
            const int cl   = q ^ (brow & 3);
            bfr[ni] = *(const bf16x8*)&Bs[cur][brow * BK + (cl << 3)];
        }
#pragma unroll
        for (int mi = 0; mi < 4; ++mi)
#pragma unroll
            for (int ni = 0; ni < 4; ++ni)
                acc[mi][ni] = __builtin_amdgcn_mfma_f32_16x16x32_bf16(
                    af[mi], bfr[ni], acc[mi][ni], 0, 0, 0);
    }

    // epilogue: C/D layout col = lane&15, row = (lane>>4)*4 + j (verified R1)
    const int r0 = (lane >> 4) * 4;
    const int c  = lane & 15;
    float bias_n[4];
#pragma unroll
    for (int ni = 0; ni < 4; ++ni)
        bias_n[ni] = Bias[grp * DOUT + bn0 + wn + ni * 16 + c];
#pragma unroll
    for (int mi = 0; mi < 4; ++mi) {
#pragma unroll
        for (int j = 0; j < 4; ++j) {
            const int row = bm0 + wm + mi * 16 + r0 + j;
            float* yrow = Y + (size_t)row * (NGRP * DOUT) + grp * DOUT + bn0 + wn;
#pragma unroll
            for (int ni = 0; ni < 4; ++ni)
                yrow[ni * 16 + c] = acc[mi][ni][j] + bias_n[ni];
        }
    }
#undef DMA_A
#undef DMA_B
}

extern "C" void kernel_launch(void* const* d_in, const int* in_sizes, int n_in,
                              void* d_out, int out_size, void* d_ws, size_t ws_size,
                              hipStream_t stream) {
    const float* X    = (const float*)d_in[0];
    const float* W    = (const float*)d_in[1];
    const float* Bias = (const float*)d_in[2];
    float* Y          = (float*)d_out;
    __bf16* Wb        = (__bf16*)d_ws;   // 8 MB scratch

    // prepass: 16*512*512 = 4M elems / (256 thr * 8 elems) = 2048 blocks
    wcvt_kernel<<<2048, 256, 0, stream>>>(W, Wb);

    const int grid = NGRP * (BATCH / BM) * (DOUT / BN);  // 16*32*4 = 2048
    MultiLinear_48498770706571_kernel<<<grid, 256, 0, stream>>>(X, Wb, Bias, Y);
}

// Round 12
// 100.022 us; speedup vs baseline: 1.2117x; 1.2117x over previous
//
#include <hip/hip_runtime.h>
#include <hip/hip_bf16.h>

// MultiLinear: y[b,g,o] = sum_i x[b,g,i] * W[g,o,i] + bias[g,o]
// B=4096, G=16, DIN=512, DOUT=512, fp32 in/out.
// R12: ALL-DMA depth-2 pipeline. 256x256 tile, BK=32, 8 waves.
//  - A staged as RAW FP32 via global_load_lds (no X prepass); fp32->bf16
//    cvt at consume time, in-register. B staged bf16 from W-prepass (d_ws).
//  - TRIPLE-buffered LDS (3 x 48 KB = 144 KB): DMA for tile kt+2 issued at
//    tile kt -> 2 full compute phases of latency cover.
//  - One raw barrier per K-tile; pre-barrier wait is COUNTED vmcnt(6): only
//    tile kt's DMA (issued 2 phases ago) drains; tile kt+1 stays in flight.
//    No wave-side staging => barrier waits on nothing hot (T3/T4 finally
//    applicable; R5/R9/R11 all had staging serial inside the phase).
//  - Uniform-bank LDS reads via XOR chunk swizzle (T21 both-sides: linear
//    DMA dest + inverse-swizzled global source + swizzled ds_read):
//    A: chunk c^(r&7) over 8 positions; B: c^(r&3) + row-parity interleave.
//    Both give exactly 8 dwords/bank/instr = hardware minimum.

#define BATCH 4096
#define NGRP  16
#define DIN   512
#define DOUT  512

#define BM 256
#define BN 256
#define BK 32
#define NT (DIN / BK)   // 16 K-tiles

typedef __bf16 bf16x8 __attribute__((ext_vector_type(8)));
typedef float  f32x4  __attribute__((ext_vector_type(4)));
typedef const __attribute__((address_space(1))) void gas_void;
typedef __attribute__((address_space(3))) void las_void;

// ---------- prepass: W fp32 -> bf16 into d_ws (canonical layout) ----------
__global__ __launch_bounds__(256)
void wcvt_kernel(const float* __restrict__ W, __bf16* __restrict__ Wb) {
    const int i = (blockIdx.x * 256 + threadIdx.x) * 8;
    f32x4 a = *(const f32x4*)(W + i);
    f32x4 b = *(const f32x4*)(W + i + 4);
    bf16x8 v;
#pragma unroll
    for (int j = 0; j < 4; ++j) { v[j] = (__bf16)a[j]; v[j + 4] = (__bf16)b[j]; }
    *(bf16x8*)(Wb + i) = v;
}

// ---------- main GEMM ----------
__global__ __launch_bounds__(512, 2)
void MultiLinear_48498770706571_kernel(const float* __restrict__ X,
                                       const __bf16* __restrict__ Wb,
                                       const float* __restrict__ Bias,
                                       float* __restrict__ Y) {
    // 512 blocks / 8 XCDs = 64 consecutive tiles (2 full groups) per XCD.
    const int bid = (blockIdx.x & 7) * 64 + (blockIdx.x >> 3);
    const int g   = bid >> 5;          // 32 tiles per group (16 m x 2 n)
    const int mt  = (bid >> 1) & 15;
    const int nt  = bid & 1;
    const int bm0 = mt * BM;
    const int bn0 = nt * BN;

    __shared__ float  As[3][BM * BK];   // 3 x 32 KB, fp32, DMA-filled
    __shared__ __bf16 Bs[3][BN * BK];   // 3 x 16 KB, bf16, DMA-filled

    const int tid  = threadIdx.x;
    const int lane = tid & 63;
    const int w    = tid >> 6;        // 0..7
    const int wm   = (w >> 2) * 128;  // {0,128}
    const int wn   = (w & 3) * 64;    // {0,64,128,192}
    const int l15  = lane & 15;
    const int q    = lane >> 4;       // 0..3: k-granule (8 elems) of MFMA frag

    // A-DMA lane geometry: each instr = 8 rows x 128 B (1 KB).
    const int arow_l = lane >> 3;     // 0..7 row within instr
    const int ac     = lane & 7;      // 16B chunk 0..7 within row
    // B-DMA lane geometry: each instr = 16 rows x 64 B (1 KB).
    const int brow_l = lane >> 2;     // 0..15 row within instr
    const int bc     = lane & 3;      // 16B chunk 0..3 within row

    const float*  xbase = X + ((size_t)bm0 * NGRP + g) * DIN;
    const __bf16* wbase = Wb + (size_t)(g * DOUT + bn0) * DIN;

    // A: LDS chunk c of row r holds GLOBAL chunk c^(r&7)  (XOR involution)
#define DMA_A(kt, buf)                                                     \
    do {                                                                   \
        _Pragma("unroll")                                                  \
        for (int q4 = 0; q4 < 4; ++q4) {                                   \
            const int row0 = (w << 5) + (q4 << 3);                         \
            const int r    = row0 + arow_l;                                \
            const int sc   = ac ^ (r & 7);                                 \
            const float* gp = xbase + (size_t)r * (NGRP * DIN)             \
                              + (kt) * BK + (sc << 2);                     \
            __builtin_amdgcn_global_load_lds(                              \
                (gas_void*)gp, (las_void*)&As[buf][row0 * BK], 16, 0, 0);  \
        }                                                                  \
    } while (0)

    // B: LDS chunk c of row r holds GLOBAL chunk c^(r&3)
#define DMA_B(kt, buf)                                                     \
    do {                                                                   \
        _Pragma("unroll")                                                  \
        for (int q2 = 0; q2 < 2; ++q2) {                                   \
            const int row0 = (w << 5) + (q2 << 4);                         \
            const int r    = row0 + brow_l;                                \
            const int sc   = bc ^ (r & 3);                                 \
            const __bf16* gp = wbase + (size_t)r * DIN                     \
                               + (kt) * BK + (sc << 3);                    \
            __builtin_amdgcn_global_load_lds(                              \
                (gas_void*)gp, (las_void*)&Bs[buf][row0 * BK], 16, 0, 0);  \
        }                                                                  \
    } while (0)

#define COMPUTE(buf)                                                       \
    do {                                                                   \
        bf16x8 af[8], bfr[4];                                              \
        _Pragma("unroll")                                                  \
        for (int mi = 0; mi < 8; ++mi) {                                   \
            const int r   = wm + mi * 16 + l15;                            \
            const int ca0 = (2 * q) ^ (r & 7);                             \
            const int ca1 = (2 * q + 1) ^ (r & 7);                         \
            f32x4 x0 = *(const f32x4*)&As[buf][r * BK + (ca0 << 2)];       \
            f32x4 x1 = *(const f32x4*)&As[buf][r * BK + (ca1 << 2)];       \
            _Pragma("unroll")                                              \
            for (int j = 0; j < 4; ++j) {                                  \
                af[mi][j]     = (__bf16)x0[j];                             \
                af[mi][j + 4] = (__bf16)x1[j];                             \
            }                                                              \
        }                                                                  \
        _Pragma("unroll")                                                  \
        for (int ni = 0; ni < 4; ++ni) {                                   \
            const int rb = wn + ni * 16 + l15;                             \
            const int cb = q ^ (rb & 3);                                   \
            bfr[ni] = *(const bf16x8*)&Bs[buf][rb * BK + (cb << 3)];       \
        }                                                                  \
        _Pragma("unroll")                                                  \
        for (int mi = 0; mi < 8; ++mi)                                     \
            _Pragma("unroll")                                              \
            for (int ni = 0; ni < 4; ++ni)                                 \
                acc[mi][ni] = __builtin_amdgcn_mfma_f32_16x16x32_bf16(     \
                    af[mi], bfr[ni], acc[mi][ni], 0, 0, 0);                \
    } while (0)

    f32x4 acc[8][4];
#pragma unroll
    for (int mi = 0; mi < 8; ++mi)
#pragma unroll
        for (int ni = 0; ni < 4; ++ni) acc[mi][ni] = f32x4{0.f, 0.f, 0.f, 0.f};

    // prologue: tiles 0 and 1 in flight (12 DMA ops/wave outstanding)
    DMA_A(0, 0); DMA_B(0, 0);
    DMA_A(1, 1); DMA_B(1, 1);

    int b_cur = 0;
    for (int kt = 0; kt < NT; ++kt) {
        // Wait for tile kt's DMA (issued 2 phases ago; 6 newer ops = tile
        // kt+1 stay in flight). Tail: only tile kt outstanding -> vmcnt(0).
        if (kt + 1 < NT)
            asm volatile("s_waitcnt vmcnt(6)" ::: "memory");
        else
            asm volatile("s_waitcnt vmcnt(0)" ::: "memory");
        asm volatile("s_waitcnt lgkmcnt(0)" ::: "memory");
        __builtin_amdgcn_s_barrier();

        // refill buffer (kt+2)%3 = (kt-1)%3: its readers finished compute
        // kt-1, which all waves completed before the barrier above. WAR-safe.
        if (kt + 2 < NT) {
            const int b_n2 = b_cur < 1 ? b_cur + 2 : b_cur - 1;  // (kt+2)%3
            DMA_A(kt + 2, b_n2);
            DMA_B(kt + 2, b_n2);
        }

        COMPUTE(b_cur);

        b_cur = b_cur < 2 ? b_cur + 1 : 0;
    }

    // epilogue: C/D layout col = lane&15, row = (lane>>4)*4 + j (verified R1)
    const int r0 = (lane >> 4) * 4;
    const int c  = lane & 15;
    float bias_n[4];
#pragma unroll
    for (int ni = 0; ni < 4; ++ni)
        bias_n[ni] = Bias[g * DOUT + bn0 + wn + ni * 16 + c];
#pragma unroll
    for (int mi = 0; mi < 8; ++mi) {
#pragma unroll
        for (int j = 0; j < 4; ++j) {
            const int row = bm0 + wm + mi * 16 + r0 + j;
            float* yrow = Y + (size_t)row * (NGRP * DOUT) + g * DOUT + bn0 + wn;
#pragma unroll
            for (int ni = 0; ni < 4; ++ni)
                yrow[ni * 16 + c] = acc[mi][ni][j] + bias_n[ni];
        }
    }
#undef DMA_A
#undef DMA_B
#undef COMPUTE
}

extern "C" void kernel_launch(void* const* d_in, const int* in_sizes, int n_in,
                              void* d_out, int out_size, void* d_ws, size_t ws_size,
                              hipStream_t stream) {
    const float* X    = (const float*)d_in[0];
    const float* W    = (const float*)d_in[1];
    const float* Bias = (const float*)d_in[2];
    float* Y          = (float*)d_out;
    __bf16* Wb        = (__bf16*)d_ws;   // 8 MB scratch

    // prepass: 16*512*512 = 4M elems / (256 thr * 8 elems) = 2048 blocks
    wcvt_kernel<<<2048, 256, 0, stream>>>(W, Wb);

    const int grid = NGRP * (BATCH / BM) * (DOUT / BN);  // 16*16*2 = 512
    MultiLinear_48498770706571_kernel<<<grid, 512, 0, stream>>>(X, Wb, Bias, Y);
}

// Round 13
// 86.472 us; speedup vs baseline: 1.4016x; 1.1567x over previous
//
#include <hip/hip_runtime.h>
#include <hip/hip_bf16.h>

// MultiLinear: y[b,g,o] = sum_i x[b,g,i] * W[g,o,i] + bias[g,o]
// B=4096, G=16, DIN=512, DOUT=512, fp32 in/out.
// R13 = R9 (best, 84us) + ONE fix: A-tile LDS layout. R4-R9 used a 72-elem
// (144 B = 36-dword) padded row stride; 36 = 4 mod 32 -> A ds_read_b128 hit
// only 8 of 32 banks = 8-way conflict (~2.9x, m136). New layout: linear
// 128 B rows with 16B-chunk XOR swizzle (phys_chunk = chunk ^ (row&7)) on
// both the cvt-write and frag-read sides -> exact bank floor (2-way only).
// B-side unchanged (bf16 prepass + global_load_lds DMA, chunk-XOR swizzle,
// counted vmcnt(8) that never drains the A prefetch).

#define BATCH 4096
#define NGRP  16
#define DIN   512
#define DOUT  512

#define BM 256
#define BN 256
#define BK 64
#define NT (DIN / BK)   // 8 K-tiles

typedef __bf16 bf16x8 __attribute__((ext_vector_type(8)));
typedef float  f32x4  __attribute__((ext_vector_type(4)));
typedef const __attribute__((address_space(1))) void gas_void;
typedef __attribute__((address_space(3))) void las_void;

// ---------- prepass: W fp32 -> bf16 into d_ws ----------
__global__ __launch_bounds__(256)
void wcvt_kernel(const float* __restrict__ W, __bf16* __restrict__ Wb) {
    const int i = (blockIdx.x * 256 + threadIdx.x) * 8;
    f32x4 a = *(const f32x4*)(W + i);
    f32x4 b = *(const f32x4*)(W + i + 4);
    bf16x8 v;
#pragma unroll
    for (int j = 0; j < 4; ++j) { v[j] = (__bf16)a[j]; v[j + 4] = (__bf16)b[j]; }
    *(bf16x8*)(Wb + i) = v;
}

// ---------- main GEMM ----------
__global__ __launch_bounds__(512, 2)
void MultiLinear_48498770706571_kernel(const float* __restrict__ X,
                                       const __bf16* __restrict__ Wb,
                                       const float* __restrict__ Bias,
                                       float* __restrict__ Y) {
    // 512 blocks / 8 XCDs = 64 consecutive tiles (2 full groups) per XCD.
    const int bid = (blockIdx.x & 7) * 64 + (blockIdx.x >> 3);
    const int g   = bid >> 5;          // 32 tiles per group (16 m x 2 n)
    const int mt  = (bid >> 1) & 15;
    const int nt  = bid & 1;
    const int bm0 = mt * BM;
    const int bn0 = nt * BN;

    __shared__ __bf16 As[2][BM * BK];    // 64 KB: linear 128B rows, chunk-swz
    __shared__ __bf16 BsF[2][BN * BK];   // 64 KB: linear, DMA-filled, chunk-swz

    const int tid  = threadIdx.x;
    const int lane = tid & 63;
    const int w    = tid >> 6;        // 0..7
    const int wm   = (w >> 2) * 128;  // {0,128}
    const int wn   = (w & 3) * 64;    // {0,64,128,192}
    const int l15  = lane & 15;
    const int q    = lane >> 4;       // 0..3

    // A staging: 128 rows/pass (4 thr/row, 16 floats each), 2 passes.
    const int srow = tid >> 2;        // 0..127
    const int sc2  = (tid & 3) * 2;   // first 16B-chunk index (of 8) this thr writes
    const float* pA = X + (size_t)(bm0 + srow) * (NGRP * DIN) + g * DIN + (tid & 3) * 16;
    const size_t strideA = (size_t)128 * (NGRP * DIN);

    // B DMA geometry: per wave 32 rows; 4 issues of 1 KB (8 rows x 128 B).
    const int drow0 = (w << 5) + (lane >> 3);   // + q*8
    const int dch   = lane & 7;                 // 16 B chunk within row
    const __bf16* wbase = Wb + (size_t)g * (DOUT * DIN) + (size_t)bn0 * DIN;

    f32x4 ra[2][4];   // 32 VGPRs in flight (A only; B is DMA)

#define ISSUE_A(k0)                                                        \
    do {                                                                   \
        const f32x4* qa0 = (const f32x4*)(pA + (k0));                      \
        const f32x4* qa1 = (const f32x4*)(pA + strideA + (k0));            \
        ra[0][0] = qa0[0]; ra[0][1] = qa0[1]; ra[0][2] = qa0[2]; ra[0][3] = qa0[3]; \
        ra[1][0] = qa1[0]; ra[1][1] = qa1[1]; ra[1][2] = qa1[2]; ra[1][3] = qa1[3]; \
    } while (0)

    // A write: row r, logical chunks sc2, sc2+1 -> physical chunk ^ (r&7).
#define CVT_WRITE_A(buf)                                                   \
    do {                                                                   \
        _Pragma("unroll")                                                  \
        for (int p = 0; p < 2; ++p) {                                      \
            bf16x8 v0, v1;                                                 \
            _Pragma("unroll")                                              \
            for (int j = 0; j < 4; ++j) {                                  \
                v0[j] = (__bf16)ra[p][0][j]; v0[j + 4] = (__bf16)ra[p][1][j]; \
                v1[j] = (__bf16)ra[p][2][j]; v1[j + 4] = (__bf16)ra[p][3][j]; \
            }                                                              \
            const int row = p * 128 + srow;                                \
            const int s   = srow & 7;                                      \
            __bf16* base = &As[buf][row * BK];                             \
            *(bf16x8*)&base[((sc2 ^ s) << 3)]       = v0;                  \
            *(bf16x8*)&base[(((sc2 + 1) ^ s) << 3)] = v1;                  \
        }                                                                  \
    } while (0)

    // B: LDS linear dest; global source pre-swizzled; reads swizzle back.
#define DMA_B(kt, buf)                                                     \
    do {                                                                   \
        const size_t k0 = (size_t)(kt) * BK;                               \
        _Pragma("unroll")                                                  \
        for (int qq = 0; qq < 4; ++qq) {                                   \
            const int row = drow0 + (qq << 3);                             \
            const __bf16* gp = wbase + (size_t)row * DIN + k0              \
                               + ((dch ^ (row & 7)) << 3);                 \
            __builtin_amdgcn_global_load_lds(                              \
                (gas_void*)gp,                                             \
                (las_void*)&BsF[buf][(w << 11) + (qq << 9)], 16, 0, 0);    \
        }                                                                  \
    } while (0)

#define COMPUTE(buf)                                                       \
    do {                                                                   \
        _Pragma("unroll")                                                  \
        for (int kk = 0; kk < 2; ++kk) {                                   \
            bf16x8 af[8], bfr[4];                                          \
            _Pragma("unroll")                                              \
            for (int mi = 0; mi < 8; ++mi) {                               \
                const int row = wm + mi * 16 + l15;                        \
                const int ch  = ((kk << 2) + q) ^ (row & 7);               \
                af[mi] = *(const bf16x8*)&As[buf][row * BK + (ch << 3)];   \
            }                                                              \
            _Pragma("unroll")                                              \
            for (int ni = 0; ni < 4; ++ni) {                               \
                const int brow = wn + ni * 16 + l15;                       \
                const int ch = ((kk << 2) + q) ^ (brow & 7);               \
                bfr[ni] = *(const bf16x8*)&BsF[buf][brow * BK + (ch << 3)]; \
            }                                                              \
            _Pragma("unroll")                                              \
            for (int mi = 0; mi < 8; ++mi)                                 \
                _Pragma("unroll")                                          \
                for (int ni = 0; ni < 4; ++ni)                             \
                    acc[mi][ni] = __builtin_amdgcn_mfma_f32_16x16x32_bf16( \
                        af[mi], bfr[ni], acc[mi][ni], 0, 0, 0);            \
        }                                                                  \
    } while (0)

    f32x4 acc[8][4];
#pragma unroll
    for (int mi = 0; mi < 8; ++mi)
#pragma unroll
        for (int ni = 0; ni < 4; ++ni) acc[mi][ni] = f32x4{0.f, 0.f, 0.f, 0.f};

    // prologue: A(0) regs + DMA B(0) into buf0; write A(0); prefetch A(1).
    ISSUE_A(0);
    DMA_B(0, 0);
    CVT_WRITE_A(0);      // waits ra(0) (vmcnt 4), DMA(0) stays in flight
    ISSUE_A(BK);         // outstanding: DMA(0)[4] + A(1)[8]

    for (int kt = 0; kt < NT; ++kt) {
        const int cur = kt & 1;
        // Drain DMA(kt): outstanding = DMA(kt)[4 oldest] + A(kt+1)[8 newer].
        if (kt + 1 < NT)
            asm volatile("s_waitcnt vmcnt(8)" ::: "memory");
        else
            asm volatile("s_waitcnt vmcnt(0)" ::: "memory");  // tail: DMA only
        asm volatile("s_waitcnt lgkmcnt(0)" ::: "memory");
        __builtin_amdgcn_s_barrier();

        // after barrier: all waves done reading buf cur^1 -> WAR-safe refill.
        if (kt + 1 < NT) DMA_B(kt + 1, cur ^ 1);

        COMPUTE(cur);

        if (kt + 1 < NT) {
            CVT_WRITE_A(cur ^ 1);          // drains A(kt+1), leaves DMA in flight
            if (kt + 2 < NT) ISSUE_A((kt + 2) * BK);
        }
    }

    // epilogue: C/D layout col = lane&15, row = (lane>>4)*4 + j (verified R1)
    const int r0 = (lane >> 4) * 4;
    const int c  = lane & 15;
    float bias_n[4];
#pragma unroll
    for (int ni = 0; ni < 4; ++ni)
        bias_n[ni] = Bias[g * DOUT + bn0 + wn + ni * 16 + c];
#pragma unroll
    for (int mi = 0; mi < 8; ++mi) {
#pragma unroll
        for (int j = 0; j < 4; ++j) {
            const int row = bm0 + wm + mi * 16 + r0 + j;
            float* yrow = Y + (size_t)row * (NGRP * DOUT) + g * DOUT + bn0 + wn;
#pragma unroll
            for (int ni = 0; ni < 4; ++ni)
                yrow[ni * 16 + c] = acc[mi][ni][j] + bias_n[ni];
        }
    }
#undef ISSUE_A
#undef CVT_WRITE_A
#undef DMA_B
#undef COMPUTE
}

extern "C" void kernel_launch(void* const* d_in, const int* in_sizes, int n_in,
                              void* d_out, int out_size, void* d_ws, size_t ws_size,
                              hipStream_t stream) {
    const float* X    = (const float*)d_in[0];
    const float* W    = (const float*)d_in[1];
    const float* Bias = (const float*)d_in[2];
    float* Y          = (float*)d_out;
    __bf16* Wb        = (__bf16*)d_ws;   // 8 MB scratch

    // prepass: 16*512*512 = 4M elems / (256 thr * 8 elems) = 2048 blocks
    wcvt_kernel<<<2048, 256, 0, stream>>>(W, Wb);

    const int grid = NGRP * (BATCH / BM) * (DOUT / BN);  // 512
    MultiLinear_48498770706571_kernel<<<grid, 512, 0, stream>>>(X, Wb, Bias, Y);
}